// Round 12
// baseline (350.854 us; speedup 1.0000x reference)
//
#include <hip/hip_runtime.h>

#define BB 512
#define II 1152
#define OO 10
#define DD 16
#define JJ 8
#define OD 160           // OO*DD
#define KK (II*JJ)       // 9216

// s_part config
#define BT 64            // b-tile
#define NBT (BB/BT)      // 8
#define IC 16            // i-chunk
#define NS (II/IC)       // 72

// ---------------- transpose x[b][k] -> xT[k][b] ----------------
__global__ __launch_bounds__(256) void k_transpose(const float* __restrict__ x,
                                                   float* __restrict__ xT) {
  __shared__ float tile[32][33];
  int kb = blockIdx.x;            // 288 tiles of k
  int bb = blockIdx.y;            // 16 tiles of b
  int tx = threadIdx.x & 31, ty = threadIdx.x >> 5;  // 32 x 8
  int k0 = kb * 32, b0 = bb * 32;
#pragma unroll
  for (int r = ty; r < 32; r += 8)
    tile[r][tx] = x[(size_t)(b0 + r) * KK + k0 + tx];
  __syncthreads();
#pragma unroll
  for (int r = ty; r < 32; r += 8)
    xT[(size_t)(k0 + r) * BB + b0 + tx] = tile[tx][r];
}

// ---------------- fill c with uniform 1/1152 (softmax of zeros) ----------------
__global__ __launch_bounds__(256) void k_fill(float* __restrict__ c) {
  c[blockIdx.x * 256 + threadIdx.x] = 1.0f / 1152.0f;
}

// ---------------- b update (from agreep[od][i]) + softmax over i ----------------
__global__ __launch_bounds__(256) void k_bupd_softmax(float* __restrict__ b_ij,
                                                      const float* __restrict__ agreep,
                                                      float* __restrict__ c) {
  int o = blockIdx.x, t = threadIdx.x;
  __shared__ float buf[II];
  __shared__ float red[4];
  float mx = -1e30f;
  for (int i = t; i < II; i += 256) {
    float a = 0.f;
#pragma unroll
    for (int d = 0; d < 16; ++d) a += agreep[(size_t)(o * 16 + d) * II + i];
    float val = b_ij[i * OO + o] + a * (1.0f / (float)BB);
    b_ij[i * OO + o] = val;
    buf[i] = val;
    mx = fmaxf(mx, val);
  }
  for (int off = 32; off; off >>= 1) mx = fmaxf(mx, __shfl_down(mx, off));
  if ((t & 63) == 0) red[t >> 6] = mx;
  __syncthreads();
  mx = fmaxf(fmaxf(red[0], red[1]), fmaxf(red[2], red[3]));
  __syncthreads();
  float sum = 0.f;
  for (int i = t; i < II; i += 256) {
    float e = expf(buf[i] - mx);
    buf[i] = e;
    sum += e;
  }
  for (int off = 32; off; off >>= 1) sum += __shfl_down(sum, off);
  if ((t & 63) == 0) red[t >> 6] = sum;
  __syncthreads();
  sum = red[0] + red[1] + red[2] + red[3];
  float inv = 1.0f / sum;
  for (int i = t; i < II; i += 256) c[i * OO + o] = buf[i] * inv;
}

// ---------------- s partials: spart[ch][b][od] ----------------
// block (bt, ch): 64 b x 160 od x 16 i. thread: 4 b x 10 od.
// T14: W/c for chunk g+1 prefetched into regs during compute of g.
// LDS = max(wc 5120, half-epilogue 32x164=5248) = 21 KB -> 4 blocks/CU.
__global__ __launch_bounds__(256) void k_s_part(const float* __restrict__ xT,
                                                const float* __restrict__ W,
                                                const float* __restrict__ c,
                                                float* __restrict__ spart) {
  __shared__ float smem[5248];
  int bt = blockIdx.x;              // 0..7
  int ch = blockIdx.y;              // 0..71
  int b0 = bt * BT;
  int i0 = ch * IC;
  int t = threadIdx.x;
  int bq = t & 15;   // b = b0 + bq*4 + bb
  int og = t >> 4;   // od = og*10 + r
  float acc[4][10];
#pragma unroll
  for (int bb = 0; bb < 4; ++bb)
#pragma unroll
    for (int r = 0; r < 10; ++r) acc[bb][r] = 0.f;

  // stage-load indices for this thread (5 float4 of the 1280-f4 wc tile)
  int s_ii[5], s_rem[5], s_o[5];
#pragma unroll
  for (int q = 0; q < 5; ++q) {
    int e4 = q * 256 + t;
    s_ii[q] = e4 / 320;
    s_rem[q] = e4 - s_ii[q] * 320;
    s_o[q] = s_rem[q] >> 5;
  }
  // prologue: load stage for g=0
  float4 wreg[5];
  float creg[5];
#pragma unroll
  for (int q = 0; q < 5; ++q) {
    wreg[q] = *(const float4*)&W[(size_t)(i0 + s_ii[q]) * 1280 + s_rem[q] * 4];
    creg[q] = c[(i0 + s_ii[q]) * OO + s_o[q]];
  }

  for (int g = 0; g < 4; ++g) {
    int ig = i0 + g * 4;
    __syncthreads();                 // prior compute done reading smem
#pragma unroll
    for (int q = 0; q < 5; ++q) {
      float4 r4;
      r4.x = wreg[q].x * creg[q]; r4.y = wreg[q].y * creg[q];
      r4.z = wreg[q].z * creg[q]; r4.w = wreg[q].w * creg[q];
      *(float4*)&smem[s_ii[q] * 1280 + s_rem[q] * 4] = r4;
    }
    __syncthreads();
    if (g < 3) {                     // prefetch g+1 (hides under FMA burst)
      int ig2 = i0 + (g + 1) * 4;
#pragma unroll
      for (int q = 0; q < 5; ++q) {
        wreg[q] = *(const float4*)&W[(size_t)(ig2 + s_ii[q]) * 1280 + s_rem[q] * 4];
        creg[q] = c[(ig2 + s_ii[q]) * OO + s_o[q]];
      }
    }
#pragma unroll
    for (int ii = 0; ii < 4; ++ii) {
      int i = ig + ii;
      float xr[8][4];
#pragma unroll
      for (int j = 0; j < 8; ++j) {
        float4 q4 = *(const float4*)&xT[(size_t)(i * 8 + j) * BB + b0 + bq * 4];
        xr[j][0] = q4.x; xr[j][1] = q4.y; xr[j][2] = q4.z; xr[j][3] = q4.w;
      }
      const float* wrow = &smem[ii * 1280 + og * 80];
#pragma unroll
      for (int r = 0; r < 10; ++r) {
        float4 w0 = *(const float4*)&wrow[r * 8];
        float4 w1 = *(const float4*)&wrow[r * 8 + 4];
#pragma unroll
        for (int bb = 0; bb < 4; ++bb) {
          float a = acc[bb][r];
          a = fmaf(xr[0][bb], w0.x, a);
          a = fmaf(xr[1][bb], w0.y, a);
          a = fmaf(xr[2][bb], w0.z, a);
          a = fmaf(xr[3][bb], w0.w, a);
          a = fmaf(xr[4][bb], w1.x, a);
          a = fmaf(xr[5][bb], w1.y, a);
          a = fmaf(xr[6][bb], w1.z, a);
          a = fmaf(xr[7][bb], w1.w, a);
          acc[bb][r] = a;
        }
      }
    }
  }
  // epilogue: two 32-row transpose passes reusing smem (keeps LDS at 21 KB)
#pragma unroll
  for (int h = 0; h < 2; ++h) {
    __syncthreads();
    if ((bq >> 3) == h) {
#pragma unroll
      for (int bb = 0; bb < 4; ++bb)
#pragma unroll
        for (int r = 0; r < 10; ++r)
          smem[((bq & 7) * 4 + bb) * 164 + og * 10 + r] = acc[bb][r];
    }
    __syncthreads();
    float* dst = &spart[(size_t)ch * BB * OD + (size_t)(b0 + h * 32) * OD];
#pragma unroll
    for (int p = 0; p < 5; ++p) {
      int idx = p * 256 + t;         // float4 index over 1280
      int row = idx / 40;
      int col4 = idx - row * 40;
      float4 val = *(const float4*)&smem[row * 164 + col4 * 4];
      *(float4*)&dst[row * 160 + col4 * 4] = val;
    }
  }
}

// ---------------- reduce partials + squash ----------------
__global__ __launch_bounds__(256) void k_squash(const float* __restrict__ spart,
                                                float* __restrict__ v) {
  int t = blockIdx.x * 256 + threadIdx.x;  // over B*OD = 81920
  float s = 0.f;
#pragma unroll 8
  for (int ns = 0; ns < NS; ++ns) s += spart[(size_t)ns * (BB * OD) + t];
  float sq = s * s;
  sq += __shfl_xor(sq, 1);
  sq += __shfl_xor(sq, 2);
  sq += __shfl_xor(sq, 4);
  sq += __shfl_xor(sq, 8);
  float scale = sqrtf(sq) / (1.0f + sq);
  v[t] = s * scale;
}

// ---------------- G partials: Gp[bh][od][k] ----------------
// G[k][od] = sum_b x[b][k]*v[b][od], original x layout (k contiguous).
// Block (kt, oh, bh): 32 k x 80 od x 256 b. 128 threads: bq=t&7 -> 4 consecutive
// k (one f4 x-load, 8 lanes = 128B contiguous); og=t>>3 (16 groups) -> 5 od.
// v staged in LDS 32-b chunks (10 KB); T14: next chunk's loads issued under FMA.
__global__ __launch_bounds__(128) void k_G(const float* __restrict__ x,
                                           const float* __restrict__ v,
                                           float* __restrict__ Gp) {
  __shared__ float smem[32 * 80];   // 10 KB v-stage
  int t = threadIdx.x;
  int bq = t & 7;                   // k = k0 + bq*4 + kk
  int og = t >> 3;                  // od = ob + og*5 + r, og in [0,16)
  int k0 = blockIdx.x * 32;         // 288 k-tiles
  int oh = blockIdx.y;              // 0..1 (od half)
  int bh = blockIdx.z;              // 0..1 (b half)
  int ob = oh * 80;
  int bbase = bh * 256;

  float acc[4][5];
#pragma unroll
  for (int kk = 0; kk < 4; ++kk)
#pragma unroll
    for (int r = 0; r < 5; ++r) acc[kk][r] = 0.f;

  // prologue: load v-stage for ph=0 (5 f4/thread, 640 f4 total)
  float4 vreg[5];
#pragma unroll
  for (int p = 0; p < 5; ++p) {
    int idx = p * 128 + t;          // f4 idx in [0,640)
    int b = idx / 20, col4 = idx - b * 20;
    vreg[p] = *(const float4*)&v[(size_t)(bbase + b) * 160 + ob + col4 * 4];
  }

  for (int ph = 0; ph < 8; ++ph) {
    int bc = bbase + ph * 32;
    __syncthreads();                // prior compute done reading smem
#pragma unroll
    for (int p = 0; p < 5; ++p) {
      int idx = p * 128 + t;
      int b = idx / 20, col4 = idx - b * 20;
      *(float4*)&smem[b * 80 + col4 * 4] = vreg[p];
    }
    __syncthreads();
    if (ph < 7) {                   // prefetch next chunk under the FMA burst
      int bc2 = bc + 32;
#pragma unroll
      for (int p = 0; p < 5; ++p) {
        int idx = p * 128 + t;
        int b = idx / 20, col4 = idx - b * 20;
        vreg[p] = *(const float4*)&v[(size_t)(bc2 + b) * 160 + ob + col4 * 4];
      }
    }
#pragma unroll 4
    for (int bi = 0; bi < 32; ++bi) {
      float4 x4 = *(const float4*)&x[(size_t)(bc + bi) * KK + k0 + bq * 4];
      const float* vrow = &smem[bi * 80 + og * 5];
      float xv[4] = {x4.x, x4.y, x4.z, x4.w};
#pragma unroll
      for (int r = 0; r < 5; ++r) {
        float vv_ = vrow[r];
#pragma unroll
        for (int kk = 0; kk < 4; ++kk)
          acc[kk][r] = fmaf(xv[kk], vv_, acc[kk][r]);
      }
    }
  }
  // store: 4 consecutive k -> one f4 per od; lanes bq 0..7 = 128B contiguous
#pragma unroll
  for (int r = 0; r < 5; ++r) {
    int od = ob + og * 5 + r;
    float4 st = {acc[0][r], acc[1][r], acc[2][r], acc[3][r]};
    *(float4*)&Gp[((size_t)bh * OD + od) * KK + k0 + bq * 4] = st;
  }
}

// ---------------- agreep[od][i] = sum_{j,bh} W[i,o,d,j] * Gp[bh][od][i*8+j] ----------------
__global__ __launch_bounds__(256) void k_WGred(const float* __restrict__ W,
                                               const float* __restrict__ Gp,
                                               float* __restrict__ agreep) {
  int od = blockIdx.x;              // 160
  int o = od >> 4, d = od & 15;
  int t = threadIdx.x;
  for (int ic = 0; ic < 5; ++ic) {
    int i = ic * 256 + t;
    if (i >= II) break;
    const float* gp0 = &Gp[(size_t)od * KK + (size_t)i * 8];
    const float* gp1 = gp0 + (size_t)OD * KK;
    float4 a0 = *(const float4*)gp0;
    float4 a1 = *(const float4*)(gp0 + 4);
    float4 b0 = *(const float4*)gp1;
    float4 b1 = *(const float4*)(gp1 + 4);
    float4 g0 = {a0.x + b0.x, a0.y + b0.y, a0.z + b0.z, a0.w + b0.w};
    float4 g1 = {a1.x + b1.x, a1.y + b1.y, a1.z + b1.z, a1.w + b1.w};
    const float* wp = &W[(size_t)((i * OO + o) * DD + d) * JJ];
    float4 w0 = *(const float4*)wp;
    float4 w1 = *(const float4*)(wp + 4);
    float acc = w0.x * g0.x + w0.y * g0.y + w0.z * g0.z + w0.w * g0.w +
                w1.x * g1.x + w1.y * g1.y + w1.z * g1.z + w1.w * g1.w;
    agreep[(size_t)od * II + i] = acc;
  }
}

extern "C" void kernel_launch(void* const* d_in, const int* in_sizes, int n_in,
                              void* d_out, int out_size, void* d_ws, size_t ws_size,
                              hipStream_t stream) {
  const float* x = (const float*)d_in[0];   // [512][1152][8]
  const float* W = (const float*)d_in[1];   // [1152][10][16][8]
  float* out = (float*)d_out;               // [512][10][16][1] == flat v
  float* ws = (float*)d_ws;

  float* b_ij = ws;                 // 11520
  float* c    = ws + 11520;         // 11520
  float* vv   = ws + 23040;         // 81920
  float* xT   = ws + 186880;        // 9216*512 = 4718592
  float* sp   = ws + 4905472;       // 72*81920 = 5898240; end = 10803712 (proven fit)
  float* Gp   = sp;                 // [2][160][9216] = 2949120 (sp dead after squash)
  float* agreep = sp + 2949120;     // + 184320 <= 5898240

  hipMemsetAsync(b_ij, 0, 11520 * sizeof(float), stream);
  k_transpose<<<dim3(288, 16), 256, 0, stream>>>(x, xT);
  k_fill<<<45, 256, 0, stream>>>(c);   // softmax of zeros = uniform

  for (int it = 0; it < 3; ++it) {
    k_s_part<<<dim3(NBT, NS), 256, 0, stream>>>(xT, W, c, sp);
    k_squash<<<320, 256, 0, stream>>>(sp, it == 2 ? out : vv);
    if (it < 2) {
      k_G<<<dim3(288, 2, 2), 128, 0, stream>>>(x, vv, Gp);
      k_WGred<<<160, 256, 0, stream>>>(W, Gp, agreep);
      k_bupd_softmax<<<OO, 256, 0, stream>>>(b_ij, agreep, c);
    }
  }
}